// Round 4
// baseline (189.622 us; speedup 1.0000x reference)
//
#include <hip/hip_runtime.h>

// Problem constants (fixed by the reference):
//   TOTAL_NODES = 262144, NUM_GRAPHS = 1024, MAX_NODES = 512, D = 256
#define NUM_GRAPHS 1024
#define MAX_NODES  512
#define DIM        256
#define D4         (DIM / 4)          // 64 float4 per row

// Native clang vector type: __builtin_nontemporal_* requires a pointer to
// integer/float/vector-of-such, which HIP's float4 struct is NOT.
typedef float f4 __attribute__((ext_vector_type(4)));

// ---------------------------------------------------------------------------
// Kernel 1: boundary scan. batch_idx is sorted, so starts[g] = lower_bound(g)
// is found by comparing adjacent elements. O(n) coalesced reads, no
// dependent-load chains. starts has NUM_GRAPHS+1 entries (sentinel
// starts[1024] = n) so counts[g] = starts[g+1] - starts[g].
// Handles int64 vs int32 storage: for little-endian int64 (values < 2^31)
// the int32 view at index n-1 is a hi-word == 0; for int32 it's the max
// graph id (nonzero for this data).
// ---------------------------------------------------------------------------
__global__ void scan_offsets_kernel(const int* __restrict__ bidx32, int n,
                                    int* __restrict__ starts) {
    int i = blockIdx.x * blockDim.x + threadIdx.x;
    if (i >= n) return;
    const bool is64 = (bidx32[n - 1] == 0);
    const int cur  = is64 ? bidx32[2 * i] : bidx32[i];
    const int prev = (i == 0) ? -1 : (is64 ? bidx32[2 * (i - 1)] : bidx32[i - 1]);
    for (int g = prev + 1; g <= cur; ++g) starts[g] = i;   // usually 0 iters
    if (i == n - 1) {
        for (int g = cur + 1; g <= NUM_GRAPHS; ++g) starts[g] = n;
    }
}

// ---------------------------------------------------------------------------
// Kernel 2: enc_states + enc_mask, fused. Block b owns a CONTIGUOUS output
// region: graph g = b>>1, slot range [256*(b&1), 256*(b&1)+256) — 256 rows
// = 256 KB of output, and (when occupied) a contiguous 256 KB region of emb.
// s and c are block-uniform loop invariants (hoisted to SGPRs); the hot loop
// is a pure load->store stream with no metadata loads and no address deps.
// Wave w (of 4) covers lane 0..63 of one row per iteration; the `slot < c`
// branch is wave-uniform. Blocks with slots >= c degenerate to zero-fill.
// ---------------------------------------------------------------------------
__global__ void __launch_bounds__(256)
scatter_states_kernel(const f4* __restrict__ emb,
                      const int* __restrict__ starts,
                      f4* __restrict__ out,
                      float* __restrict__ mask) {
    const int b    = blockIdx.x;            // 0..2047
    const int g    = b >> 1;                // graph id
    const int half = b & 1;                 // 0: slots 0..255, 1: 256..511
    const int s    = starts[g];
    const int c    = starts[g + 1] - s;
    const int lane = threadIdx.x & 63;
    const int wid  = threadIdx.x >> 6;      // 0..3
    const int slot0 = half * 256 + wid;

    // Block-local output base: row (g*512 + half*256), contiguous 16384 f4.
    f4* outb = out + (size_t)(g * MAX_NODES + half * 256) * D4;

#pragma unroll 8
    for (int it = 0; it < 64; ++it) {
        const int slot = slot0 + it * 4;    // this wave's row this iteration
        f4 val = (f4)(0.f);
        if (slot < c) {
            val = __builtin_nontemporal_load(&emb[(size_t)(s + slot) * D4 + lane]);
        }
        __builtin_nontemporal_store(val, &outb[it * 256 + threadIdx.x]);
    }

    // enc_mask: this block owns 256 consecutive mask elements.
    const int mslot = half * 256 + threadIdx.x;
    __builtin_nontemporal_store((mslot < c) ? 1.0f : 0.0f,
                                &mask[g * MAX_NODES + mslot]);
}

extern "C" void kernel_launch(void* const* d_in, const int* in_sizes, int n_in,
                              void* d_out, int out_size, void* d_ws, size_t ws_size,
                              hipStream_t stream) {
    const float* node_emb = (const float*)d_in[0];
    const int*   bidx32   = (const int*)d_in[1];   // int32 view; kernels detect int64
    const int    n        = in_sizes[1];           // 262144

    int* starts = (int*)d_ws;                      // NUM_GRAPHS + 1 ints

    scan_offsets_kernel<<<(n + 255) / 256, 256, 0, stream>>>(bidx32, n, starts);

    float* mask = (float*)d_out + (size_t)NUM_GRAPHS * MAX_NODES * DIM;
    scatter_states_kernel<<<NUM_GRAPHS * 2, 256, 0, stream>>>(
        (const f4*)node_emb, starts, (f4*)d_out, mask);
}

// Round 5
// 172.277 us; speedup vs baseline: 1.1007x; 1.1007x over previous
//
#include <hip/hip_runtime.h>

// Problem constants (fixed by the reference):
//   TOTAL_NODES = 262144, NUM_GRAPHS = 1024, MAX_NODES = 512, D = 256
#define NUM_GRAPHS 1024
#define MAX_NODES  512
#define DIM        256
#define D4         (DIM / 4)          // 64 float4 per row (1 KB)

typedef float f4 __attribute__((ext_vector_type(4)));

// lower_bound over the sorted batch_idx (int64 or int32 storage).
__device__ __forceinline__ int lower_bound_idx(const int* __restrict__ b, int n,
                                               bool is64, int key) {
    int lo = 0, hi = n;
    while (lo < hi) {
        int mid = (lo + hi) >> 1;
        int v = is64 ? b[2 * mid] : b[mid];
        if (v < key) lo = mid + 1; else hi = mid;
    }
    return lo;
}

// ---------------------------------------------------------------------------
// Single fused kernel. Block b owns graph g = b>>1, slot range
// [256*(b&1), 256*(b&1)+256) — a contiguous 256 KB output span. Threads 0/1
// binary-search starts[g] / starts[g+1] (bidx is 1-2 MB, L2-resident after
// first touches; ~18 dependent L2 hits ≈ 1.5 us, parallel across all 2048
// blocks) — no separate offsets kernel, no inter-kernel barrier.
// Each wave then streams a contiguous 64-row (64 KB) range: a copy loop for
// occupied rows followed by a zero-fill loop. Plain (cached) loads/stores —
// the configuration the 6.3 TB/s copy and 6.7 TB/s fill ceilings use;
// nontemporal hints removed (suspected store-path line-fetch penalty).
// ---------------------------------------------------------------------------
__global__ void __launch_bounds__(256)
scatter_states_kernel(const f4* __restrict__ emb,
                      const int* __restrict__ bidx32, int n,
                      f4* __restrict__ out, float* __restrict__ mask) {
    __shared__ int sc[2];
    const int b    = blockIdx.x;        // 0..2047
    const int g    = b >> 1;            // graph id
    const int half = b & 1;             // 0: slots 0..255, 1: 256..511

    if (threadIdx.x < 2) {
        // int64 detect: little-endian int64 values < 2^31 => int32 view at
        // index n-1 is a hi-word == 0; int32 => it's the max graph id (!=0).
        const bool is64 = (bidx32[n - 1] == 0);
        sc[threadIdx.x] = lower_bound_idx(bidx32, n, is64, g + threadIdx.x);
    }
    __syncthreads();
    const int s = sc[0];
    const int c = sc[1] - sc[0];

    const int lane  = threadIdx.x & 63;
    const int w     = threadIdx.x >> 6;       // wave 0..3
    const int rbase = half * 256 + w * 64;    // this wave's first slot

    // Per-wave contiguous streams: 64 rows x 1 KB.
    const f4* wemb = emb + (size_t)(s + rbase) * D4 + lane;
    f4*       wout = out + ((size_t)g * MAX_NODES + rbase) * D4 + lane;

    int ncopy = c - rbase;                    // occupied rows in this range
    ncopy = ncopy < 0 ? 0 : (ncopy > 64 ? 64 : ncopy);

    int it = 0;
#pragma unroll 8
    for (; it < ncopy; ++it)
        wout[it * D4] = wemb[it * D4];
    const f4 z = (f4)(0.f);
#pragma unroll 8
    for (; it < 64; ++it)
        wout[it * D4] = z;

    // enc_mask: this block's 256 consecutive mask elements (f32 0/1).
    const int mslot = half * 256 + threadIdx.x;
    mask[(size_t)g * MAX_NODES + mslot] = (mslot < c) ? 1.0f : 0.0f;
}

extern "C" void kernel_launch(void* const* d_in, const int* in_sizes, int n_in,
                              void* d_out, int out_size, void* d_ws, size_t ws_size,
                              hipStream_t stream) {
    const float* node_emb = (const float*)d_in[0];
    const int*   bidx32   = (const int*)d_in[1];   // int32 view; kernel detects int64
    const int    n        = in_sizes[1];           // 262144

    float* mask = (float*)d_out + (size_t)NUM_GRAPHS * MAX_NODES * DIM;
    scatter_states_kernel<<<NUM_GRAPHS * 2, 256, 0, stream>>>(
        (const f4*)node_emb, bidx32, n, (f4*)d_out, mask);
}